// Round 4
// baseline (2849.802 us; speedup 1.0000x reference)
//
#include <hip/hip_runtime.h>
#include <hip/hip_bf16.h>

#define T_SEQ 256
#define BATCH 256
#define HID   1024
#define EMB   10
#define VOCABN 10
#define NCLS  10

typedef __attribute__((ext_vector_type(8))) short short8;
typedef __attribute__((ext_vector_type(4))) float floatx4;
typedef unsigned long long ull;

// ---- workspace layout (bytes) ----
#define OFF_WHB   0                                // 4096*1024 bf16 = 8 MB
#define OFF_PTAB  (8*1024*1024)                    // 10*4096 f32 = 160 KB
#define OFF_H0    (OFF_PTAB + 160*1024)            // 256*1024 bf16 = 512 KB
#define OFF_H1    (OFF_H0 + BATCH*HID*2)
#define OFF_BAR   (OFF_H1 + BATCH*HID*2)           // [0,1024) quarter ctrs, [1024,1032) XCD slot ctrs

// Spin bound: ~30ms of polls. Never hit when the protocol is healthy; converts
// any broken-link hang into a diagnosable failed-verification run (r3 lesson).
#define SPIN_BOUND (1u << 17)

// hwreg(HW_REG_XCC_ID=20, offset=0, width=32) -> 20 | (31<<11) = 63508
#define HWREG_XCC_ID_FULL 63508

__device__ __forceinline__ float fsig(float x) {
    return __builtin_amdgcn_rcpf(1.0f + __expf(-x));
}
__device__ __forceinline__ float ftanh(float x) {
    return 2.0f * fsig(2.0f * x) - 1.0f;
}

// TCC-executed atomic add returning old value. Global atomics execute in the
// L2 (no L1 atomics on CDNA) -> L1-immune read of the current L2 value.
// Inline asm: cannot be idempotent-folded into a (L1-cacheable) plain load.
// No sc1 -> executes at the LOCAL XCD's TCC (our coherence point by design).
__device__ __forceinline__ unsigned atomic_add_ret_l2(unsigned* p, unsigned v) {
    unsigned old;
    asm volatile("global_atomic_add %0, %1, %2, off sc0\n\ts_waitcnt vmcnt(0)"
                 : "=v"(old) : "v"(p), "v"(v) : "memory");
    return old;
}
__device__ __forceinline__ void atomic_add_l2(unsigned* p, unsigned v) {
    asm volatile("global_atomic_add %0, %1, off" :: "v"(p), "v"(v) : "memory");
}

// One-shot prep: cast Wh -> bf16 gate-major; build ptab; zero h0/h1 + counters.
__global__ __launch_bounds__(256)
void prep_kernel(const float* __restrict__ Wgh, const float* __restrict__ Wih,
                 const float* __restrict__ Wfh, const float* __restrict__ Woh,
                 const float* __restrict__ embed,
                 const float* __restrict__ Wgx, const float* __restrict__ Wix,
                 const float* __restrict__ Wfx, const float* __restrict__ Wox,
                 const float* __restrict__ bg, const float* __restrict__ bi,
                 const float* __restrict__ bf, const float* __restrict__ bo,
                 __hip_bfloat16* __restrict__ whb, float* __restrict__ ptab,
                 __hip_bfloat16* __restrict__ h0, __hip_bfloat16* __restrict__ h1,
                 unsigned* __restrict__ bar)
{
    int idx = blockIdx.x * 256 + threadIdx.x;   // 0 .. 4194303
    {
        int gate = idx >> 20;
        int rem  = idx & 0xFFFFF;
        const float* W = (gate == 0) ? Wgh : (gate == 1) ? Wih : (gate == 2) ? Wfh : Woh;
        whb[idx] = __float2bfloat16(W[rem]);
    }
    if (idx < VOCABN * 4 * HID) {               // ptab[v*4096 + g]
        int v = idx >> 12;
        int g = idx & 4095;
        int gg = g >> 10;
        int j  = g & 1023;
        const float* Wx = (gg == 0) ? Wgx : (gg == 1) ? Wix : (gg == 2) ? Wfx : Wox;
        const float* bb = (gg == 0) ? bg  : (gg == 1) ? bi  : (gg == 2) ? bf  : bo;
        float s = bb[j];
        #pragma unroll
        for (int e = 0; e < EMB; ++e) s += embed[v * EMB + e] * Wx[j * EMB + e];
        ptab[idx] = s;
    }
    if (idx < BATCH * HID) {
        h0[idx] = __float2bfloat16(0.0f);
        h1[idx] = __float2bfloat16(0.0f);       // insurance: bounded values if raced
    }
    if (idx < 8 * 4 * 32 + 8) bar[idx] = 0u;    // quarter counters + XCD slot counters
}

// Persistent LSTM, weights stationary in registers for all 256 timesteps.
// Grid 256 WGs x 256 thr; ~85KB LDS -> 1 WG/CU forced; 256 CUs -> pigeonhole
// gives exactly 32 WGs per XCD. Each WG reads its physical XCD (s_getreg
// XCC_ID) and claims (bt=xcd, ht=slot), so producers/consumers of a batch
// group share one XCD and the h exchange lives in that XCD's L2:
//   - h stores: plain (write-through L1 -> local L2; ack from TCC so
//     s_waitcnt vmcnt(0) => L2-visible)
//   - counters: TCC-executed asm atomics (L1-immune; r3 showed sc0 loads do
//     NOT bypass L1 on gfx950 -> polls starved at full spin-bound, A stale)
//   - A-loads: plain dwordx4 AFTER an acquire-agent fence (buffer_inv) that
//     invalidates L1; refill comes from local L2 dirty lines (no fabric).
// Release order: wave drains stores (vmcnt 0) then lane 0 bumps its quarter
// counter -> consumer target 32 signals/step (8 WGs x 4 waves).
// WAR on the h ping-pong is transitive: step-t+1 stores happen after spins
// observed all 32 step-t signals, each issued after that WG's reduction
// barrier, i.e. after all its waves' step-t A-loads retired.
__global__ __launch_bounds__(256, 1)
void lstm_persist(const int* __restrict__ x, const float* __restrict__ ptab,
                  const __hip_bfloat16* __restrict__ whb,
                  __hip_bfloat16* __restrict__ h0buf,
                  __hip_bfloat16* __restrict__ h1buf,
                  unsigned* __restrict__ bar)
{
    __shared__ float red[4 * 2 * 8 * 320];   // [wave][m][n][col*20+row] = 80 KB
    __shared__ float pt[VOCABN * 128];       // [v][g][jj2] = 5 KB
    __shared__ int s_grp[2];

    const int tid  = threadIdx.x;
    const int w    = tid >> 6;
    const int lane = tid & 63;
    const int l16  = lane & 15;
    const int quad = lane >> 4;

    // ---- runtime XCD discovery + slot claim (correct under ANY dispatch map).
    if (tid == 0) {
        unsigned xcd = __builtin_amdgcn_s_getreg(HWREG_XCC_ID_FULL) & 7u;
        unsigned slot = atomic_add_ret_l2(bar + 1024 + xcd, 1u);
        s_grp[0] = (int)xcd;
        s_grp[1] = (int)(slot & 31u);
    }
    __syncthreads();
    const int bt = s_grp[0];                  // batch group == physical XCD
    const int ht = s_grp[1];                  // 0..31 hidden tile (claim order)
    const int j0 = ht << 5;
    const int b0 = bt << 5;
    const int mw = w >> 1;                    // owned m-tile (post-reduction)
    const int jb = w & 1;                     // owned 16-col half of the 32-hid tile

    unsigned* myq  = bar + ((bt << 2) + w) * 32;          // quarter this wave consumes
    unsigned* sigq = bar + ((bt << 2) + (ht >> 3)) * 32;  // quarter this WG produces

    // Stage ptab slice: pt[v*128 + g*32 + jj2]
    for (int i = tid; i < VOCABN * 128; i += 256) {
        int v = i >> 7, r = i & 127, g = r >> 5, jj2 = r & 31;
        pt[i] = ptab[v * 4096 + g * 1024 + j0 + jj2];
    }

    // Stationary B fragments: n-frag n -> gate n>>1, col-half (n&1)*16.
    short8 Bf[8][8];
    #pragma unroll
    for (int n = 0; n < 8; ++n) {
        const short* p = (const short*)whb + (((size_t)(n >> 1)) << 20)
                       + (((size_t)(j0 + ((n & 1) << 4) + l16)) << 10)
                       + (w << 8) + (quad << 3);
        #pragma unroll
        for (int kc = 0; kc < 8; ++kc)
            Bf[n][kc] = *(const short8*)(p + kc * 32);
    }

    float cst[4] = {0.f, 0.f, 0.f, 0.f};
    __syncthreads();                          // pt ready

    ull hinA  = (ull)h0buf;
    ull houtA = (ull)h1buf;
    const int brow = (mw << 4) + (quad << 2); // owned batch-row base (local)

    #pragma unroll 1
    for (int t = 0; t < T_SEQ; ++t) {
        // x fetch first (independent of h readiness).
        int xv[4];
        #pragma unroll
        for (int r = 0; r < 4; ++r) xv[r] = x[(b0 + brow + r) * T_SEQ + t];

        // ---- per-wave spin on the 32 producer-wave signals of K-quarter w.
        // Poll = TCC atomic add(0): reads the true L2 value every iteration.
        if (t) {
            unsigned tgt = (unsigned)(t << 5);
            if (lane == 0) {
                for (unsigned it = 0; it < SPIN_BOUND; ++it) {
                    if (atomic_add_ret_l2(myq, 0u) >= tgt) break;
                    __builtin_amdgcn_s_sleep(4);
                }
            }
            // Acquire at agent scope: s_waitcnt + buffer_inv (L1 invalidate).
            // Subsequent plain A-loads refill from the local L2, where the
            // producers' drained write-through stores live (dirty lines
            // survive an invalidate). Compiler-emitted = correct gfx950 bits.
            __builtin_amdgcn_fence(__ATOMIC_ACQUIRE, "agent");
        }

        // ---- partial GEMM over this wave's K-slice: 2 m-tiles x 8 n-frags.
        const ull* Au = (const ull*)hinA + (((size_t)(b0 + l16)) << 8) + (w << 6) + (quad << 1);
        floatx4 acc[2][8];
        #pragma unroll
        for (int m = 0; m < 2; ++m) {
            short8 Af[8];
            const ull* Ab = Au + (m << 12);
            #pragma unroll
            for (int kc = 0; kc < 8; ++kc)
                Af[kc] = *(const short8*)(Ab + kc * 8);
            asm volatile("s_waitcnt vmcnt(0)" ::: "memory");
            __builtin_amdgcn_sched_barrier(0);
            #pragma unroll
            for (int n = 0; n < 8; ++n) {
                floatx4 a = {0.f, 0.f, 0.f, 0.f};
                #pragma unroll
                for (int kc = 0; kc < 8; ++kc)
                    a = __builtin_amdgcn_mfma_f32_16x16x32_bf16(Af[kc], Bf[n][kc], a, 0, 0, 0);
                acc[m][n] = a;
            }
        }

        // ---- K-reduction through LDS; wave w owns (m=mw, col-half jb).
        #pragma unroll
        for (int m = 0; m < 2; ++m)
            #pragma unroll
            for (int n = 0; n < 8; ++n)
                *(floatx4*)&red[(((w * 2 + m) * 8 + n) * 320) + l16 * 20 + quad * 4] = acc[m][n];
        __syncthreads();

        floatx4 z[4];
        #pragma unroll
        for (int g = 0; g < 4; ++g) {
            int n = (g << 1) + jb;
            floatx4 s = *(floatx4*)&red[((mw * 8 + n) * 320) + l16 * 20 + quad * 4];
            #pragma unroll
            for (int wp = 1; wp < 4; ++wp)
                s += *(floatx4*)&red[(((wp * 2 + mw) * 8 + n) * 320) + l16 * 20 + quad * 4];
            z[g] = s;
        }

        // ---- gates + register-resident c + plain h store (write-through to local L2).
        __hip_bfloat16* ho = (__hip_bfloat16*)houtA;
        const int jcol = j0 + (jb << 4) + l16;
        #pragma unroll
        for (int r = 0; r < 4; ++r) {
            int pb = (xv[r] << 7) + (jb << 4) + l16;
            float zg = z[0][r] + pt[pb];
            float zi = z[1][r] + pt[pb + 32];
            float zf = z[2][r] + pt[pb + 64];
            float zo = z[3][r] + pt[pb + 96];
            float gv = ftanh(zg), iv = fsig(zi), fv = fsig(zf), ov = fsig(zo);
            float cn = gv * iv + cst[r] * fv;
            cst[r] = cn;
            ho[(((size_t)(b0 + brow + r)) << 10) + jcol] = __float2bfloat16(ftanh(cn) * ov);
        }

        // ---- per-wave early signal: drain THIS wave's stores to the local L2
        // (store-ack comes from TCC), then one TCC-local add.
        if (t != T_SEQ - 1) {
            asm volatile("s_waitcnt vmcnt(0)" ::: "memory");
            if (lane == 0)
                atomic_add_l2(sigq, 1u);
        }

        // red-buffer WAR protection for the next step (off the signal path).
        __syncthreads();

        ull tmp = hinA; hinA = houtA; houtA = tmp;
    }
}

// y = h @ W_ph^T + b_p : one wave per batch row.
__global__ __launch_bounds__(256)
void final_kernel(const __hip_bfloat16* __restrict__ h, const float* __restrict__ Wph,
                  const float* __restrict__ bp, float* __restrict__ y)
{
    int w = threadIdx.x >> 6;
    int lane = threadIdx.x & 63;
    int b = blockIdx.x * 4 + w;
    float acc[NCLS];
    #pragma unroll
    for (int k = 0; k < NCLS; ++k) acc[k] = 0.0f;
    for (int k = lane; k < HID; k += 64) {
        float hv = __bfloat162float(h[b * HID + k]);
        #pragma unroll
        for (int cls = 0; cls < NCLS; ++cls) acc[cls] += hv * Wph[cls * HID + k];
    }
    #pragma unroll
    for (int cls = 0; cls < NCLS; ++cls) {
        float v = acc[cls];
        #pragma unroll
        for (int off = 32; off > 0; off >>= 1) v += __shfl_down(v, off);
        if (lane == 0) y[b * NCLS + cls] = v + bp[cls];
    }
}

extern "C" void kernel_launch(void* const* d_in, const int* in_sizes, int n_in,
                              void* d_out, int out_size, void* d_ws, size_t ws_size,
                              hipStream_t stream)
{
    const int*   x     = (const int*)d_in[0];
    const float* embed = (const float*)d_in[1];
    const float* Wgx   = (const float*)d_in[2];
    const float* Wix   = (const float*)d_in[3];
    const float* Wfx   = (const float*)d_in[4];
    const float* Wox   = (const float*)d_in[5];
    const float* Wgh   = (const float*)d_in[6];
    const float* Wih   = (const float*)d_in[7];
    const float* Wfh   = (const float*)d_in[8];
    const float* Woh   = (const float*)d_in[9];
    const float* Wph   = (const float*)d_in[10];
    const float* bg    = (const float*)d_in[11];
    const float* bi    = (const float*)d_in[12];
    const float* bf    = (const float*)d_in[13];
    const float* bo    = (const float*)d_in[14];
    const float* bp    = (const float*)d_in[15];
    float* out = (float*)d_out;

    char* ws = (char*)d_ws;
    __hip_bfloat16* whb  = (__hip_bfloat16*)(ws + OFF_WHB);
    float*          ptab = (float*)(ws + OFF_PTAB);
    __hip_bfloat16* h0   = (__hip_bfloat16*)(ws + OFF_H0);
    __hip_bfloat16* h1   = (__hip_bfloat16*)(ws + OFF_H1);
    unsigned*       bar  = (unsigned*)(ws + OFF_BAR);

    prep_kernel<<<16384, 256, 0, stream>>>(Wgh, Wih, Wfh, Woh, embed,
                                           Wgx, Wix, Wfx, Wox,
                                           bg, bi, bf, bo,
                                           whb, ptab, h0, h1, bar);

    lstm_persist<<<256, 256, 0, stream>>>(x, ptab, whb, h0, h1, bar);

    // T=256 even -> final h lives in h0.
    final_kernel<<<64, 256, 0, stream>>>(h0, Wph, bp, out);
}

// Round 5
// 1461.228 us; speedup vs baseline: 1.9503x; 1.9503x over previous
//
#include <hip/hip_runtime.h>
#include <hip/hip_bf16.h>

#define T_SEQ 256
#define BATCH 256
#define HID   1024
#define EMB   10
#define VOCABN 10
#define NCLS  10

typedef __attribute__((ext_vector_type(8))) short short8;
typedef __attribute__((ext_vector_type(4))) float floatx4;
typedef unsigned long long ull;

// ---- workspace layout (bytes) ----
#define OFF_WHB   0                                // 4096*1024 bf16 = 8 MB
#define OFF_PTAB  (8*1024*1024)                    // 10*4096 f32 = 160 KB
#define OFF_H0    (OFF_PTAB + 160*1024)            // 256*1024 bf16 = 512 KB
#define OFF_H1    (OFF_H0 + BATCH*HID*2)
#define OFF_BAR   (OFF_H1 + BATCH*HID*2)           // [0,1024) quarter ctrs; [1024,1280) XCD slot ctrs (1/line)

// Spin bound: ~30ms of polls. Never hit when the protocol is healthy; converts
// any broken-link hang into a diagnosable failed-verification run (r3 lesson).
#define SPIN_BOUND (1u << 17)

// hwreg(HW_REG_XCC_ID=20, offset=0, width=32) -> 20 | (31<<11) = 63508
#define HWREG_XCC_ID_FULL 63508

__device__ __forceinline__ float fsig(float x) {
    return __builtin_amdgcn_rcpf(1.0f + __expf(-x));
}
__device__ __forceinline__ float ftanh(float x) {
    return 2.0f * fsig(2.0f * x) - 1.0f;
}

// TCC-executed atomic add returning old value. Global atomics execute in the
// L2 (no L1 atomics on CDNA) -> L1-immune read of the current L2 value.
// No sc1 -> executes at the LOCAL XCD's TCC (our coherence point by design).
// Proven working in r4.
__device__ __forceinline__ unsigned atomic_add_ret_l2(unsigned* p, unsigned v) {
    unsigned old;
    asm volatile("global_atomic_add %0, %1, %2, off sc0\n\ts_waitcnt vmcnt(0)"
                 : "=v"(old) : "v"(p), "v"(v) : "memory");
    return old;
}
__device__ __forceinline__ void atomic_add_l2(unsigned* p, unsigned v) {
    asm volatile("global_atomic_add %0, %1, off" :: "v"(p), "v"(v) : "memory");
}

// One-shot prep: cast Wh -> bf16 gate-major; build ptab; zero h0/h1 + counters.
__global__ __launch_bounds__(256)
void prep_kernel(const float* __restrict__ Wgh, const float* __restrict__ Wih,
                 const float* __restrict__ Wfh, const float* __restrict__ Woh,
                 const float* __restrict__ embed,
                 const float* __restrict__ Wgx, const float* __restrict__ Wix,
                 const float* __restrict__ Wfx, const float* __restrict__ Wox,
                 const float* __restrict__ bg, const float* __restrict__ bi,
                 const float* __restrict__ bf, const float* __restrict__ bo,
                 __hip_bfloat16* __restrict__ whb, float* __restrict__ ptab,
                 __hip_bfloat16* __restrict__ h0, __hip_bfloat16* __restrict__ h1,
                 unsigned* __restrict__ bar)
{
    int idx = blockIdx.x * 256 + threadIdx.x;   // 0 .. 4194303
    {
        int gate = idx >> 20;
        int rem  = idx & 0xFFFFF;
        const float* W = (gate == 0) ? Wgh : (gate == 1) ? Wih : (gate == 2) ? Wfh : Woh;
        whb[idx] = __float2bfloat16(W[rem]);
    }
    if (idx < VOCABN * 4 * HID) {               // ptab[v*4096 + g]
        int v = idx >> 12;
        int g = idx & 4095;
        int gg = g >> 10;
        int j  = g & 1023;
        const float* Wx = (gg == 0) ? Wgx : (gg == 1) ? Wix : (gg == 2) ? Wfx : Wox;
        const float* bb = (gg == 0) ? bg  : (gg == 1) ? bi  : (gg == 2) ? bf  : bo;
        float s = bb[j];
        #pragma unroll
        for (int e = 0; e < EMB; ++e) s += embed[v * EMB + e] * Wx[j * EMB + e];
        ptab[idx] = s;
    }
    if (idx < BATCH * HID) {
        h0[idx] = __float2bfloat16(0.0f);
        h1[idx] = __float2bfloat16(0.0f);       // insurance: bounded values if raced
    }
    if (idx < 1280) bar[idx] = 0u;              // quarter ctrs + padded slot ctrs
}

// Persistent LSTM, weights stationary in registers for all 256 timesteps.
// Grid 256 WGs x 256 thr; ~85KB LDS -> 1 WG/CU forced; 256 CUs -> pigeonhole
// gives exactly 32 WGs per XCD. Each WG reads its physical XCD (s_getreg
// XCC_ID) and claims (bt=xcd, ht=slot), so producers/consumers of a batch
// group share one XCD and the h exchange lives in that XCD's L2:
//   - h stores: plain (write-through L1 -> local L2; ack from TCC so
//     s_waitcnt vmcnt(0) => L2-visible before the signal)
//   - counters: TCC-executed asm atomics (L1-immune; r3 proved sc0 loads do
//     NOT bypass L1 on gfx950)
//   - A-loads: __builtin_nontemporal_load (nt = no L1 allocate). h addresses
//     are loaded ONLY via nt and never by plain loads, so no h line is ever
//     L1-resident -> every A-load is serviced by the local L2 = always fresh.
//     This replaces r4's per-wave per-step acquire-agent fence (buffer_inv),
//     which cost pipe stalls and correlated with a 100 KB/step HBM leak.
//   - XCD slot counters padded to one cache line each: r4 kept all 8 in one
//     line, RMW'd by 8 non-coherent TCCs -> line-writeback could clobber a
//     neighbor's claim (the intermittent 34 ms / bound-exhaust dispatch).
// Release order: wave drains stores (vmcnt 0) then lane 0 bumps its quarter
// counter -> consumer target 32 signals/step (8 WGs x 4 waves).
// WAR on the h ping-pong is transitive: step-t+2 stores of buffer P happen
// after observing all step-t+1 signals; each WG's t+1 signal postdates its
// t+1 reduction barrier, which postdates its step-t A-loads of P retiring.
__global__ __launch_bounds__(256, 1)
void lstm_persist(const int* __restrict__ x, const float* __restrict__ ptab,
                  const __hip_bfloat16* __restrict__ whb,
                  __hip_bfloat16* __restrict__ h0buf,
                  __hip_bfloat16* __restrict__ h1buf,
                  unsigned* __restrict__ bar)
{
    __shared__ float red[4 * 2 * 8 * 320];   // [wave][m][n][col*20+row] = 80 KB
    __shared__ float pt[VOCABN * 128];       // [v][g][jj2] = 5 KB
    __shared__ int s_grp[2];

    const int tid  = threadIdx.x;
    const int w    = tid >> 6;
    const int lane = tid & 63;
    const int l16  = lane & 15;
    const int quad = lane >> 4;

    // ---- runtime XCD discovery + slot claim (correct under ANY dispatch map).
    if (tid == 0) {
        unsigned xcd = __builtin_amdgcn_s_getreg(HWREG_XCC_ID_FULL) & 7u;
        unsigned slot = atomic_add_ret_l2(bar + 1024 + xcd * 32, 1u);
        s_grp[0] = (int)xcd;
        s_grp[1] = (int)(slot & 31u);
    }
    __syncthreads();
    const int bt = s_grp[0];                  // batch group == physical XCD
    const int ht = s_grp[1];                  // 0..31 hidden tile (claim order)
    const int j0 = ht << 5;
    const int b0 = bt << 5;
    const int mw = w >> 1;                    // owned m-tile (post-reduction)
    const int jb = w & 1;                     // owned 16-col half of the 32-hid tile

    unsigned* myq  = bar + ((bt << 2) + w) * 32;          // quarter this wave consumes
    unsigned* sigq = bar + ((bt << 2) + (ht >> 3)) * 32;  // quarter this WG produces

    // Stage ptab slice: pt[v*128 + g*32 + jj2]
    for (int i = tid; i < VOCABN * 128; i += 256) {
        int v = i >> 7, r = i & 127, g = r >> 5, jj2 = r & 31;
        pt[i] = ptab[v * 4096 + g * 1024 + j0 + jj2];
    }

    // Stationary B fragments: n-frag n -> gate n>>1, col-half (n&1)*16.
    short8 Bf[8][8];
    #pragma unroll
    for (int n = 0; n < 8; ++n) {
        const short* p = (const short*)whb + (((size_t)(n >> 1)) << 20)
                       + (((size_t)(j0 + ((n & 1) << 4) + l16)) << 10)
                       + (w << 8) + (quad << 3);
        #pragma unroll
        for (int kc = 0; kc < 8; ++kc)
            Bf[n][kc] = *(const short8*)(p + kc * 32);
    }

    float cst[4] = {0.f, 0.f, 0.f, 0.f};
    __syncthreads();                          // pt ready

    ull hinA  = (ull)h0buf;
    ull houtA = (ull)h1buf;
    const int brow = (mw << 4) + (quad << 2); // owned batch-row base (local)

    #pragma unroll 1
    for (int t = 0; t < T_SEQ; ++t) {
        // x fetch first (independent of h readiness).
        int xv[4];
        #pragma unroll
        for (int r = 0; r < 4; ++r) xv[r] = x[(b0 + brow + r) * T_SEQ + t];

        // ---- per-wave spin on the 32 producer-wave signals of K-quarter w.
        // Poll = TCC atomic add(0): reads the true L2 value every iteration.
        if (t) {
            unsigned tgt = (unsigned)(t << 5);
            if (lane == 0) {
                for (unsigned it = 0; it < SPIN_BOUND; ++it) {
                    if (atomic_add_ret_l2(myq, 0u) >= tgt) break;
                    __builtin_amdgcn_s_sleep(2);
                }
            }
        }

        // ---- A-fragment loads: all 16 nt loads in flight, ONE L2 round trip.
        // nt = no L1 allocate -> always serviced by local L2 (fresh h).
        const ull* Au = (const ull*)hinA + (((size_t)(b0 + l16)) << 8) + (w << 6) + (quad << 1);
        short8 Af[2][8];
        #pragma unroll
        for (int kc = 0; kc < 8; ++kc)
            Af[0][kc] = __builtin_nontemporal_load((const short8*)(Au + kc * 8));
        #pragma unroll
        for (int kc = 0; kc < 8; ++kc)
            Af[1][kc] = __builtin_nontemporal_load((const short8*)(Au + 4096 + kc * 8));

        // ---- partial GEMM over this wave's K-slice: 2 m-tiles x 8 n-frags.
        floatx4 acc[2][8];
        #pragma unroll
        for (int m = 0; m < 2; ++m) {
            #pragma unroll
            for (int n = 0; n < 8; ++n) {
                floatx4 a = {0.f, 0.f, 0.f, 0.f};
                #pragma unroll
                for (int kc = 0; kc < 8; ++kc)
                    a = __builtin_amdgcn_mfma_f32_16x16x32_bf16(Af[m][kc], Bf[n][kc], a, 0, 0, 0);
                acc[m][n] = a;
            }
        }

        // ---- K-reduction through LDS; wave w owns (m=mw, col-half jb).
        #pragma unroll
        for (int m = 0; m < 2; ++m)
            #pragma unroll
            for (int n = 0; n < 8; ++n)
                *(floatx4*)&red[(((w * 2 + m) * 8 + n) * 320) + l16 * 20 + quad * 4] = acc[m][n];
        __syncthreads();

        floatx4 z[4];
        #pragma unroll
        for (int g = 0; g < 4; ++g) {
            int n = (g << 1) + jb;
            floatx4 s = *(floatx4*)&red[((mw * 8 + n) * 320) + l16 * 20 + quad * 4];
            #pragma unroll
            for (int wp = 1; wp < 4; ++wp)
                s += *(floatx4*)&red[(((wp * 2 + mw) * 8 + n) * 320) + l16 * 20 + quad * 4];
            z[g] = s;
        }

        // ---- gates + register-resident c + plain h store (write-through to local L2).
        __hip_bfloat16* ho = (__hip_bfloat16*)houtA;
        const int jcol = j0 + (jb << 4) + l16;
        #pragma unroll
        for (int r = 0; r < 4; ++r) {
            int pb = (xv[r] << 7) + (jb << 4) + l16;
            float zg = z[0][r] + pt[pb];
            float zi = z[1][r] + pt[pb + 32];
            float zf = z[2][r] + pt[pb + 64];
            float zo = z[3][r] + pt[pb + 96];
            float gv = ftanh(zg), iv = fsig(zi), fv = fsig(zf), ov = fsig(zo);
            float cn = gv * iv + cst[r] * fv;
            cst[r] = cn;
            ho[(((size_t)(b0 + brow + r)) << 10) + jcol] = __float2bfloat16(ftanh(cn) * ov);
        }

        // ---- per-wave early signal: drain THIS wave's stores to the local L2
        // (store-ack comes from TCC), then one TCC-local add.
        if (t != T_SEQ - 1) {
            asm volatile("s_waitcnt vmcnt(0)" ::: "memory");
            if (lane == 0)
                atomic_add_l2(sigq, 1u);
        }

        // red-buffer WAR protection for the next step (off the signal path).
        __syncthreads();

        ull tmp = hinA; hinA = houtA; houtA = tmp;
    }
}

// y = h @ W_ph^T + b_p : one wave per batch row.
__global__ __launch_bounds__(256)
void final_kernel(const __hip_bfloat16* __restrict__ h, const float* __restrict__ Wph,
                  const float* __restrict__ bp, float* __restrict__ y)
{
    int w = threadIdx.x >> 6;
    int lane = threadIdx.x & 63;
    int b = blockIdx.x * 4 + w;
    float acc[NCLS];
    #pragma unroll
    for (int k = 0; k < NCLS; ++k) acc[k] = 0.0f;
    for (int k = lane; k < HID; k += 64) {
        float hv = __bfloat162float(h[b * HID + k]);
        #pragma unroll
        for (int cls = 0; cls < NCLS; ++cls) acc[cls] += hv * Wph[cls * HID + k];
    }
    #pragma unroll
    for (int cls = 0; cls < NCLS; ++cls) {
        float v = acc[cls];
        #pragma unroll
        for (int off = 32; off > 0; off >>= 1) v += __shfl_down(v, off);
        if (lane == 0) y[b * NCLS + cls] = v + bp[cls];
    }
}

extern "C" void kernel_launch(void* const* d_in, const int* in_sizes, int n_in,
                              void* d_out, int out_size, void* d_ws, size_t ws_size,
                              hipStream_t stream)
{
    const int*   x     = (const int*)d_in[0];
    const float* embed = (const float*)d_in[1];
    const float* Wgx   = (const float*)d_in[2];
    const float* Wix   = (const float*)d_in[3];
    const float* Wfx   = (const float*)d_in[4];
    const float* Wox   = (const float*)d_in[5];
    const float* Wgh   = (const float*)d_in[6];
    const float* Wih   = (const float*)d_in[7];
    const float* Wfh   = (const float*)d_in[8];
    const float* Woh   = (const float*)d_in[9];
    const float* Wph   = (const float*)d_in[10];
    const float* bg    = (const float*)d_in[11];
    const float* bi    = (const float*)d_in[12];
    const float* bf    = (const float*)d_in[13];
    const float* bo    = (const float*)d_in[14];
    const float* bp    = (const float*)d_in[15];
    float* out = (float*)d_out;

    char* ws = (char*)d_ws;
    __hip_bfloat16* whb  = (__hip_bfloat16*)(ws + OFF_WHB);
    float*          ptab = (float*)(ws + OFF_PTAB);
    __hip_bfloat16* h0   = (__hip_bfloat16*)(ws + OFF_H0);
    __hip_bfloat16* h1   = (__hip_bfloat16*)(ws + OFF_H1);
    unsigned*       bar  = (unsigned*)(ws + OFF_BAR);

    prep_kernel<<<16384, 256, 0, stream>>>(Wgh, Wih, Wfh, Woh, embed,
                                           Wgx, Wix, Wfx, Wox,
                                           bg, bi, bf, bo,
                                           whb, ptab, h0, h1, bar);

    lstm_persist<<<256, 256, 0, stream>>>(x, ptab, whb, h0, h1, bar);

    // T=256 even -> final h lives in h0.
    final_kernel<<<64, 256, 0, stream>>>(h0, Wph, bp, out);
}

// Round 6
// 1421.515 us; speedup vs baseline: 2.0048x; 1.0279x over previous
//
#include <hip/hip_runtime.h>
#include <hip/hip_bf16.h>

#define T_SEQ 256
#define BATCH 256
#define HID   1024
#define EMB   10
#define VOCABN 10
#define NCLS  10

typedef __attribute__((ext_vector_type(8))) short short8;
typedef __attribute__((ext_vector_type(4))) float floatx4;
typedef unsigned long long ull;

// ---- workspace layout (bytes) ----
#define OFF_WHB   0                                // 4096*1024 bf16 = 8 MB
#define OFF_PTAB  (8*1024*1024)                    // 10*4096 f32 = 160 KB
#define OFF_H0    (OFF_PTAB + 160*1024)            // 256*1024 bf16 = 512 KB
#define OFF_H1    (OFF_H0 + BATCH*HID*2)
#define OFF_BAR   (OFF_H1 + BATCH*HID*2)           // [0,1024) quarter ctrs; [1024,1280) XCD slot ctrs (1/line)

// Spin bound: ~30ms of polls. Never hit when the protocol is healthy; converts
// any broken-link hang into a diagnosable failed-verification run (r3 lesson).
#define SPIN_BOUND (1u << 17)

// hwreg(HW_REG_XCC_ID=20, offset=0, width=32) -> 20 | (31<<11) = 63508
#define HWREG_XCC_ID_FULL 63508

__device__ __forceinline__ float fsig(float x) {
    return __builtin_amdgcn_rcpf(1.0f + __expf(-x));
}
__device__ __forceinline__ float ftanh(float x) {
    return 2.0f * fsig(2.0f * x) - 1.0f;
}

// TCC-executed atomic add returning old value. Global atomics execute in the
// L2 (no L1 atomics on CDNA) -> L1-immune read of the current L2 value.
// No sc1 -> executes at the LOCAL XCD's TCC (our coherence point by design).
// Proven working in r4/r5.
__device__ __forceinline__ unsigned atomic_add_ret_l2(unsigned* p, unsigned v) {
    unsigned old;
    asm volatile("global_atomic_add %0, %1, %2, off sc0\n\ts_waitcnt vmcnt(0)"
                 : "=v"(old) : "v"(p), "v"(v) : "memory");
    return old;
}
__device__ __forceinline__ void atomic_add_l2(unsigned* p, unsigned v) {
    asm volatile("global_atomic_add %0, %1, off" :: "v"(p), "v"(v) : "memory");
}

// One-shot prep: cast Wh -> bf16 gate-major; build ptab; zero h0/h1 + counters.
__global__ __launch_bounds__(256)
void prep_kernel(const float* __restrict__ Wgh, const float* __restrict__ Wih,
                 const float* __restrict__ Wfh, const float* __restrict__ Woh,
                 const float* __restrict__ embed,
                 const float* __restrict__ Wgx, const float* __restrict__ Wix,
                 const float* __restrict__ Wfx, const float* __restrict__ Wox,
                 const float* __restrict__ bg, const float* __restrict__ bi,
                 const float* __restrict__ bf, const float* __restrict__ bo,
                 __hip_bfloat16* __restrict__ whb, float* __restrict__ ptab,
                 __hip_bfloat16* __restrict__ h0, __hip_bfloat16* __restrict__ h1,
                 unsigned* __restrict__ bar)
{
    int idx = blockIdx.x * 256 + threadIdx.x;   // 0 .. 4194303
    {
        int gate = idx >> 20;
        int rem  = idx & 0xFFFFF;
        const float* W = (gate == 0) ? Wgh : (gate == 1) ? Wih : (gate == 2) ? Wfh : Woh;
        whb[idx] = __float2bfloat16(W[rem]);
    }
    if (idx < VOCABN * 4 * HID) {               // ptab[v*4096 + g]
        int v = idx >> 12;
        int g = idx & 4095;
        int gg = g >> 10;
        int j  = g & 1023;
        const float* Wx = (gg == 0) ? Wgx : (gg == 1) ? Wix : (gg == 2) ? Wfx : Wox;
        const float* bb = (gg == 0) ? bg  : (gg == 1) ? bi  : (gg == 2) ? bf  : bo;
        float s = bb[j];
        #pragma unroll
        for (int e = 0; e < EMB; ++e) s += embed[v * EMB + e] * Wx[j * EMB + e];
        ptab[idx] = s;
    }
    if (idx < BATCH * HID) {
        h0[idx] = __float2bfloat16(0.0f);
        h1[idx] = __float2bfloat16(0.0f);       // insurance: bounded values if raced
    }
    if (idx < 1280) bar[idx] = 0u;              // quarter ctrs + padded slot ctrs
}

// Persistent LSTM, weights stationary in registers for all 256 timesteps.
// Grid 256 WGs x 256 thr; ~85KB LDS -> 1 WG/CU forced; 256 CUs -> pigeonhole
// gives exactly 32 WGs per XCD. Each WG reads its physical XCD (s_getreg
// XCC_ID) and claims (bt=xcd, ht=slot), so producers/consumers of a batch
// group share one XCD and the h exchange lives in that XCD's L2:
//   - h stores: plain (write-through L1 -> local L2; ack from TCC so
//     s_waitcnt vmcnt(0) => L2-visible before the signal)
//   - counters: TCC-executed asm atomics (L1-immune; r3 proved sc0 loads do
//     NOT bypass L1 on gfx950)
//   - A-loads: PLAIN dwordx4 loads preceded by a per-wave `buffer_inv sc0`
//     (L1-ONLY invalidate). r4's agent fence (buffer_inv sc1) invalidated L2
//     -> evicted dirty h lines -> HBM leak + stalls; r5's nt loads marked h
//     lines evict-first in L2 -> same ~100KB/step leak. Plain loads allocate
//     normally in L2 (h stays resident); the sc0 inv restores L1 freshness.
//     Each wave invs AFTER its spin, BEFORE its loads; waves only load their
//     own quarter, so cross-wave L1 wipes are harmless.
//   - XCD slot counters padded one/line (r4's cross-TCC false-sharing fix).
// Release order: wave drains stores (vmcnt 0) then lane 0 bumps its quarter
// counter -> consumer target 32 signals/step (8 WGs x 4 waves).
// WAR on the h ping-pong is transitive: step-t+2 stores of buffer P happen
// after observing all step-t+1 signals; each WG's t+1 signal postdates its
// t+1 reduction barrier, which postdates its step-t A-loads of P retiring.
__global__ __launch_bounds__(256, 1)
void lstm_persist(const int* __restrict__ x, const float* __restrict__ ptab,
                  const __hip_bfloat16* __restrict__ whb,
                  __hip_bfloat16* __restrict__ h0buf,
                  __hip_bfloat16* __restrict__ h1buf,
                  unsigned* __restrict__ bar)
{
    __shared__ float red[4 * 2 * 8 * 320];   // [wave][m][n][col*20+row] = 80 KB
    __shared__ float pt[VOCABN * 128];       // [v][g][jj2] = 5 KB
    __shared__ int s_grp[2];

    const int tid  = threadIdx.x;
    const int w    = tid >> 6;
    const int lane = tid & 63;
    const int l16  = lane & 15;
    const int quad = lane >> 4;

    // ---- runtime XCD discovery + slot claim (correct under ANY dispatch map).
    if (tid == 0) {
        unsigned xcd = __builtin_amdgcn_s_getreg(HWREG_XCC_ID_FULL) & 7u;
        unsigned slot = atomic_add_ret_l2(bar + 1024 + xcd * 32, 1u);
        s_grp[0] = (int)xcd;
        s_grp[1] = (int)(slot & 31u);
    }
    __syncthreads();
    const int bt = s_grp[0];                  // batch group == physical XCD
    const int ht = s_grp[1];                  // 0..31 hidden tile (claim order)
    const int j0 = ht << 5;
    const int b0 = bt << 5;
    const int mw = w >> 1;                    // owned m-tile (post-reduction)
    const int jb = w & 1;                     // owned 16-col half of the 32-hid tile

    unsigned* myq  = bar + ((bt << 2) + w) * 32;          // quarter this wave consumes
    unsigned* sigq = bar + ((bt << 2) + (ht >> 3)) * 32;  // quarter this WG produces

    // Stage ptab slice: pt[v*128 + g*32 + jj2]
    for (int i = tid; i < VOCABN * 128; i += 256) {
        int v = i >> 7, r = i & 127, g = r >> 5, jj2 = r & 31;
        pt[i] = ptab[v * 4096 + g * 1024 + j0 + jj2];
    }

    // Stationary B fragments: n-frag n -> gate n>>1, col-half (n&1)*16.
    short8 Bf[8][8];
    #pragma unroll
    for (int n = 0; n < 8; ++n) {
        const short* p = (const short*)whb + (((size_t)(n >> 1)) << 20)
                       + (((size_t)(j0 + ((n & 1) << 4) + l16)) << 10)
                       + (w << 8) + (quad << 3);
        #pragma unroll
        for (int kc = 0; kc < 8; ++kc)
            Bf[n][kc] = *(const short8*)(p + kc * 32);
    }

    float cst[4] = {0.f, 0.f, 0.f, 0.f};
    __syncthreads();                          // pt ready

    ull hinA  = (ull)h0buf;
    ull houtA = (ull)h1buf;
    const int brow = (mw << 4) + (quad << 2); // owned batch-row base (local)

    #pragma unroll 1
    for (int t = 0; t < T_SEQ; ++t) {
        // x fetch first (independent of h readiness).
        int xv[4];
        #pragma unroll
        for (int r = 0; r < 4; ++r) xv[r] = x[(b0 + brow + r) * T_SEQ + t];

        // ---- per-wave spin on the 32 producer-wave signals of K-quarter w.
        // Poll = TCC atomic add(0): reads the true L2 value every iteration.
        // Then L1-only invalidate so the plain A-loads below refill from the
        // (fresh, dirty-line-resident) local L2.
        if (t) {
            unsigned tgt = (unsigned)(t << 5);
            if (lane == 0) {
                for (unsigned it = 0; it < SPIN_BOUND; ++it) {
                    if (atomic_add_ret_l2(myq, 0u) >= tgt) break;
                    __builtin_amdgcn_s_sleep(2);
                }
            }
            asm volatile("buffer_inv sc0\n\ts_waitcnt vmcnt(0)" ::: "memory");
        }

        // ---- A-fragment loads: all 16 plain loads in flight, ONE L2 round trip.
        // Plain = normal L2 allocation; h lines stay L2-resident across steps.
        const ull* Au = (const ull*)hinA + (((size_t)(b0 + l16)) << 8) + (w << 6) + (quad << 1);
        short8 Af[2][8];
        #pragma unroll
        for (int kc = 0; kc < 8; ++kc)
            Af[0][kc] = *(const short8*)(Au + kc * 8);
        #pragma unroll
        for (int kc = 0; kc < 8; ++kc)
            Af[1][kc] = *(const short8*)(Au + 4096 + kc * 8);

        // ---- partial GEMM over this wave's K-slice: 2 m-tiles x 8 n-frags.
        floatx4 acc[2][8];
        #pragma unroll
        for (int m = 0; m < 2; ++m) {
            #pragma unroll
            for (int n = 0; n < 8; ++n) {
                floatx4 a = {0.f, 0.f, 0.f, 0.f};
                #pragma unroll
                for (int kc = 0; kc < 8; ++kc)
                    a = __builtin_amdgcn_mfma_f32_16x16x32_bf16(Af[m][kc], Bf[n][kc], a, 0, 0, 0);
                acc[m][n] = a;
            }
        }

        // ---- K-reduction through LDS; wave w owns (m=mw, col-half jb).
        #pragma unroll
        for (int m = 0; m < 2; ++m)
            #pragma unroll
            for (int n = 0; n < 8; ++n)
                *(floatx4*)&red[(((w * 2 + m) * 8 + n) * 320) + l16 * 20 + quad * 4] = acc[m][n];
        __syncthreads();

        floatx4 z[4];
        #pragma unroll
        for (int g = 0; g < 4; ++g) {
            int n = (g << 1) + jb;
            floatx4 s = *(floatx4*)&red[((mw * 8 + n) * 320) + l16 * 20 + quad * 4];
            #pragma unroll
            for (int wp = 1; wp < 4; ++wp)
                s += *(floatx4*)&red[(((wp * 2 + mw) * 8 + n) * 320) + l16 * 20 + quad * 4];
            z[g] = s;
        }

        // ---- gates + register-resident c + plain h store (write-through to local L2).
        __hip_bfloat16* ho = (__hip_bfloat16*)houtA;
        const int jcol = j0 + (jb << 4) + l16;
        #pragma unroll
        for (int r = 0; r < 4; ++r) {
            int pb = (xv[r] << 7) + (jb << 4) + l16;
            float zg = z[0][r] + pt[pb];
            float zi = z[1][r] + pt[pb + 32];
            float zf = z[2][r] + pt[pb + 64];
            float zo = z[3][r] + pt[pb + 96];
            float gv = ftanh(zg), iv = fsig(zi), fv = fsig(zf), ov = fsig(zo);
            float cn = gv * iv + cst[r] * fv;
            cst[r] = cn;
            ho[(((size_t)(b0 + brow + r)) << 10) + jcol] = __float2bfloat16(ftanh(cn) * ov);
        }

        // ---- per-wave early signal: drain THIS wave's stores to the local L2
        // (store-ack comes from TCC), then one TCC-local add.
        if (t != T_SEQ - 1) {
            asm volatile("s_waitcnt vmcnt(0)" ::: "memory");
            if (lane == 0)
                atomic_add_l2(sigq, 1u);
        }

        // red-buffer WAR protection for the next step (off the signal path).
        __syncthreads();

        ull tmp = hinA; hinA = houtA; houtA = tmp;
    }
}

// y = h @ W_ph^T + b_p : one wave per batch row.
__global__ __launch_bounds__(256)
void final_kernel(const __hip_bfloat16* __restrict__ h, const float* __restrict__ Wph,
                  const float* __restrict__ bp, float* __restrict__ y)
{
    int w = threadIdx.x >> 6;
    int lane = threadIdx.x & 63;
    int b = blockIdx.x * 4 + w;
    float acc[NCLS];
    #pragma unroll
    for (int k = 0; k < NCLS; ++k) acc[k] = 0.0f;
    for (int k = lane; k < HID; k += 64) {
        float hv = __bfloat162float(h[b * HID + k]);
        #pragma unroll
        for (int cls = 0; cls < NCLS; ++cls) acc[cls] += hv * Wph[cls * HID + k];
    }
    #pragma unroll
    for (int cls = 0; cls < NCLS; ++cls) {
        float v = acc[cls];
        #pragma unroll
        for (int off = 32; off > 0; off >>= 1) v += __shfl_down(v, off);
        if (lane == 0) y[b * NCLS + cls] = v + bp[cls];
    }
}

extern "C" void kernel_launch(void* const* d_in, const int* in_sizes, int n_in,
                              void* d_out, int out_size, void* d_ws, size_t ws_size,
                              hipStream_t stream)
{
    const int*   x     = (const int*)d_in[0];
    const float* embed = (const float*)d_in[1];
    const float* Wgx   = (const float*)d_in[2];
    const float* Wix   = (const float*)d_in[3];
    const float* Wfx   = (const float*)d_in[4];
    const float* Wox   = (const float*)d_in[5];
    const float* Wgh   = (const float*)d_in[6];
    const float* Wih   = (const float*)d_in[7];
    const float* Wfh   = (const float*)d_in[8];
    const float* Woh   = (const float*)d_in[9];
    const float* Wph   = (const float*)d_in[10];
    const float* bg    = (const float*)d_in[11];
    const float* bi    = (const float*)d_in[12];
    const float* bf    = (const float*)d_in[13];
    const float* bo    = (const float*)d_in[14];
    const float* bp    = (const float*)d_in[15];
    float* out = (float*)d_out;

    char* ws = (char*)d_ws;
    __hip_bfloat16* whb  = (__hip_bfloat16*)(ws + OFF_WHB);
    float*          ptab = (float*)(ws + OFF_PTAB);
    __hip_bfloat16* h0   = (__hip_bfloat16*)(ws + OFF_H0);
    __hip_bfloat16* h1   = (__hip_bfloat16*)(ws + OFF_H1);
    unsigned*       bar  = (unsigned*)(ws + OFF_BAR);

    prep_kernel<<<16384, 256, 0, stream>>>(Wgh, Wih, Wfh, Woh, embed,
                                           Wgx, Wix, Wfx, Wox,
                                           bg, bi, bf, bo,
                                           whb, ptab, h0, h1, bar);

    lstm_persist<<<256, 256, 0, stream>>>(x, ptab, whb, h0, h1, bar);

    // T=256 even -> final h lives in h0.
    final_kernel<<<64, 256, 0, stream>>>(h0, Wph, bp, out);
}